// Round 9
// baseline (572.472 us; speedup 1.0000x reference)
//
#include <hip/hip_runtime.h>
#include <hip/hip_bf16.h>

typedef __attribute__((ext_vector_type(4))) float float4v;
typedef __attribute__((ext_vector_type(8))) __bf16 bf16x8;
typedef __attribute__((ext_vector_type(8))) unsigned short ushort8v;

constexpr int NTOK = 50176;
constexpr int DIM  = 384;
constexpr int HID  = 1536;
constexpr int BM   = 64;          // tokens/block
constexpr int NTH  = 512;
constexpr int NBLK = NTOK / BM;   // 784
constexpr int CHW  = 64;          // hidden chunk width
constexpr int NCH  = HID / CHW;   // 24

// workspace (byte offsets) — PLAIN transposed bf16 images (no swizzle: B-frags
// are read directly from global/L2; a wave's 64 lanes cover a contiguous span)
constexpr int IMG_W1P = 0;                    // [1536 f][384 d], 768B rows  = W1^T
constexpr int IMG_W2P = 1179648;              // [384 d][1536 k], 3072B rows = W2^T
constexpr int IMG_WD  = 2359296;              // [32 c][384 d], 768B rows
constexpr int IMG_WUP = 2383872;              // [384 d][32 c], 64B rows
constexpr size_t WS_NEED = 2408448;           // == proven-available guard
constexpr int NELEMS = 1204224;

// LDS — only X and Hs live here now; 56K/block => 2 blocks/CU
constexpr int L_X  = 0;        // 48K  X [64][384] bf16, 768B rows, swz (r&7)<<4
constexpr int L_HS = 49152;    // 8K   Hs [64][64] bf16, 128B rows, swz (r&7)<<4 (R4-proven)
constexpr int LDSZ = 57344;

__device__ __forceinline__ unsigned short f2bf(float f) {
  __hip_bfloat16 h = __float2bfloat16(f);
  return *reinterpret_cast<unsigned short*>(&h);
}

__device__ __forceinline__ float gelu_f(float v) {
  float u = 0.7978845608f * (v + 0.044715f * v * v * v);
  float e = __expf(2.0f * u);
  float t = 1.0f - 2.0f / (e + 1.0f);
  return 0.5f * v * (1.0f + t);
}

// ---------------- pack kernel: f32 weights -> plain transposed bf16 images ----------------
__global__ __launch_bounds__(256) void pack_k(
    const float* __restrict__ W1, const float* __restrict__ W2,
    const float* __restrict__ wd, const float* __restrict__ wu,
    unsigned short* __restrict__ img)
{
  int i = blockIdx.x * 256 + threadIdx.x;
  if (i >= NELEMS) return;
  if (i < 589824) {                              // W1p[f][d] = W1[d][f]
    int f = i / 384, d = i % 384;
    img[i] = f2bf(W1[d * HID + f]);
  } else if (i < 1179648) {                      // W2p[d][k] = W2[k][d]
    int j = i - 589824;
    int d = j / 1536, k = j % 1536;
    img[i] = f2bf(W2[k * DIM + d]);
  } else if (i < 1179648 + 12288) {              // WD[c][d] = w_down[c/8][d][c%8]
    int j = i - 1179648;
    int c = j / 384, d = j % 384;
    float v = (c < 24) ? wd[(c >> 3) * (DIM * 8) + d * 8 + (c & 7)] : 0.f;
    img[i] = f2bf(v);
  } else {                                       // WUP[d][c] = w_up[c][d]
    int j = i - 1191936;
    int d = j / 32, c = j % 32;
    float v = (c < 24) ? wu[c * DIM + d] : 0.f;
    img[i] = f2bf(v);
  }
}

// ---------------- fused MLP + MoE-LoRA ----------------
__global__ __launch_bounds__(NTH, 4) void fused_k(
    const float* __restrict__ x,
    const float* __restrict__ tp,
    const int*   __restrict__ ti,
    const float* __restrict__ b1,
    const float* __restrict__ b2,
    const unsigned short* __restrict__ img,
    float* __restrict__ out)
{
  extern __shared__ char lds[];
  const int tid = threadIdx.x, wid = tid >> 6, lane = tid & 63;
  const int lrow = lane & 15, g4 = lane >> 4;
  const int blockRow = blockIdx.x * BM;
  const char* imgc = (const char*)img;

  // one wave grid serves both phases: wr in {0,1} (rows wr*32), wc in 0..3
  // G1: wave computes rows wr*32+{0,16}, f-col-tile wc*16 (of CHW=64)
  // G2: wave computes rows wr*32+{0,16}, out cols wc*96+nt*16 (acc[2][6])
  const int wr = wid >> 2, wc = wid & 3;

  // ---- prologue: X f32 -> bf16 -> L_X (swizzled 768B rows) ----
  {
    const float* xb = x + (size_t)blockRow * DIM;
    #pragma unroll
    for (int it = 0; it < 6; ++it) {
      int idx = it * NTH + tid;
      int row = idx / 48, c8 = idx % 48;
      float4v v0 = *(const float4v*)(xb + row * DIM + c8 * 8);
      float4v v1 = *(const float4v*)(xb + row * DIM + c8 * 8 + 4);
      ushort8v u;
      u[0]=f2bf(v0[0]); u[1]=f2bf(v0[1]); u[2]=f2bf(v0[2]); u[3]=f2bf(v0[3]);
      u[4]=f2bf(v1[0]); u[5]=f2bf(v1[1]); u[6]=f2bf(v1[2]); u[7]=f2bf(v1[3]);
      int byte = (row * 768 + c8 * 16) ^ ((row & 7) << 4);
      *(ushort8v*)(lds + L_X + byte) = u;
    }
  }
  __syncthreads();                               // X visible

  // ---- G1-moe: t1 = X @ WdT -> [64][32]; B direct from WD img (wc<2 only) ----
  float4v hv[2] = {};
  if (wc < 2) {
    const char* bsrc = imgc + IMG_WD + (wc * 16 + lrow) * 768 + g4 * 16;
    int ar0 = wr * 32 + lrow, ar1 = ar0 + 16;
    int s0 = (ar0 & 7) << 4, s1 = (ar1 & 7) << 4;
    int ab0 = ar0 * 768 + g4 * 16, ab1 = ar1 * 768 + g4 * 16;
    #pragma unroll
    for (int ks = 0; ks < 12; ++ks) {
      bf16x8 a0 = *(const bf16x8*)(lds + L_X + ((ab0 + ks * 64) ^ s0));
      bf16x8 a1 = *(const bf16x8*)(lds + L_X + ((ab1 + ks * 64) ^ s1));
      bf16x8 b  = *(const bf16x8*)(bsrc + ks * 64);
      hv[0] = __builtin_amdgcn_mfma_f32_16x16x32_bf16(a0, b, hv[0], 0, 0, 0);
      hv[1] = __builtin_amdgcn_mfma_f32_16x16x32_bf16(a1, b, hv[1], 0, 0, 0);
    }
  }
  // prob * gelu -> Hs (cols 32..63 get zeros; e>=3 -> p=0)
  {
    int col = wc * 16 + lrow; int e = col >> 3;
    #pragma unroll
    for (int mt = 0; mt < 2; ++mt) {
      #pragma unroll
      for (int r = 0; r < 4; ++r) {
        int row = wr * 32 + mt * 16 + g4 * 4 + r;
        int token = blockRow + row;
        float p = 0.f;
        if (e < 3) {
          int i0 = ti[token * 2], i1 = ti[token * 2 + 1];
          if (i0 == e) p += tp[token * 2];
          if (i1 == e) p += tp[token * 2 + 1];
        }
        float gv = p * gelu_f(hv[mt][r]);
        int byte = (row * 128 + col * 2) ^ ((row & 7) << 4);
        *(unsigned short*)(lds + L_HS + byte) = f2bf(gv);
      }
    }
  }
  __syncthreads();                               // Hs(moe) visible

  // ---- G2-moe: acc = Hs(0..31) @ WupT (K=32); B direct from WUP img ----
  float4v acc[2][6] = {};
  {
    bf16x8 A[2];
    #pragma unroll
    for (int mt = 0; mt < 2; ++mt) {
      int ra = wr * 32 + mt * 16 + lrow;
      A[mt] = *(const bf16x8*)(lds + L_HS + ra * 128 + ((g4 * 16) ^ ((ra & 7) << 4)));
    }
    #pragma unroll
    for (int nt = 0; nt < 6; ++nt) {
      int rd = wc * 96 + nt * 16 + lrow;
      bf16x8 b = *(const bf16x8*)(imgc + IMG_WUP + rd * 64 + g4 * 16);
      acc[0][nt] = __builtin_amdgcn_mfma_f32_16x16x32_bf16(A[0], b, acc[0][nt], 0, 0, 0);
      acc[1][nt] = __builtin_amdgcn_mfma_f32_16x16x32_bf16(A[1], b, acc[1][nt], 0, 0, 0);
    }
  }

  // ---- main loop: 24 chunks of 64 hidden; 2 barriers/chunk; weights from L2 ----
  for (int h = 0; h < NCH; ++h) {
    __syncthreads();                             // Hs readers (G2[h-1]) done

    // G1: H = X @ W1c -> [64][64]; A from L_X, B direct from W1p
    float4v hg[2] = {};
    {
      const char* bsrc = imgc + IMG_W1P + (size_t)(h * 64 + wc * 16 + lrow) * 768 + g4 * 16;
      int ar0 = wr * 32 + lrow, ar1 = ar0 + 16;
      int s0 = (ar0 & 7) << 4, s1 = (ar1 & 7) << 4;
      int ab0 = ar0 * 768 + g4 * 16, ab1 = ar1 * 768 + g4 * 16;
      #pragma unroll
      for (int ks = 0; ks < 12; ++ks) {
        bf16x8 a0 = *(const bf16x8*)(lds + L_X + ((ab0 + ks * 64) ^ s0));
        bf16x8 a1 = *(const bf16x8*)(lds + L_X + ((ab1 + ks * 64) ^ s1));
        bf16x8 b  = *(const bf16x8*)(bsrc + ks * 64);
        hg[0] = __builtin_amdgcn_mfma_f32_16x16x32_bf16(a0, b, hg[0], 0, 0, 0);
        hg[1] = __builtin_amdgcn_mfma_f32_16x16x32_bf16(a1, b, hg[1], 0, 0, 0);
      }
    }
    // bias + gelu -> Hs
    {
      int col = wc * 16 + lrow;
      float bb = b1[h * 64 + col];
      #pragma unroll
      for (int mt = 0; mt < 2; ++mt) {
        #pragma unroll
        for (int r = 0; r < 4; ++r) {
          int row = wr * 32 + mt * 16 + g4 * 4 + r;
          float gv = gelu_f(hg[mt][r] + bb);
          int byte = (row * 128 + col * 2) ^ ((row & 7) << 4);
          *(unsigned short*)(lds + L_HS + byte) = f2bf(gv);
        }
      }
    }
    __syncthreads();                             // Hs[h] visible

    // G2: acc += Hs @ W2c (K=64); A from L_HS, B direct from W2p
    #pragma unroll
    for (int kk = 0; kk < 2; ++kk) {
      bf16x8 A[2];
      #pragma unroll
      for (int mt = 0; mt < 2; ++mt) {
        int ra = wr * 32 + mt * 16 + lrow;
        A[mt] = *(const bf16x8*)(lds + L_HS + ra * 128 + ((kk * 64 + g4 * 16) ^ ((ra & 7) << 4)));
      }
      #pragma unroll
      for (int nt = 0; nt < 6; ++nt) {
        int rd = wc * 96 + nt * 16 + lrow;
        bf16x8 b = *(const bf16x8*)(imgc + IMG_W2P + (size_t)rd * 3072 + (h * 64 + kk * 32 + g4 * 8) * 2);
        acc[0][nt] = __builtin_amdgcn_mfma_f32_16x16x32_bf16(A[0], b, acc[0][nt], 0, 0, 0);
        acc[1][nt] = __builtin_amdgcn_mfma_f32_16x16x32_bf16(A[1], b, acc[1][nt], 0, 0, 0);
      }
    }
  }

  // ---- epilogue: + b2, store f32 ----
  #pragma unroll
  for (int nt = 0; nt < 6; ++nt) {
    int col = wc * 96 + nt * 16 + lrow;
    float bb = b2[col];
    #pragma unroll
    for (int mt = 0; mt < 2; ++mt) {
      #pragma unroll
      for (int r = 0; r < 4; ++r) {
        int row = wr * 32 + mt * 16 + g4 * 4 + r;
        out[(size_t)(blockRow + row) * DIM + col] = acc[mt][nt][r] + bb;
      }
    }
  }
}

extern "C" void kernel_launch(void* const* d_in, const int* in_sizes, int n_in,
                              void* d_out, int out_size, void* d_ws, size_t ws_size,
                              hipStream_t stream) {
  const float* x          = (const float*)d_in[0];
  const float* topk_probs = (const float*)d_in[2];
  const int*   topk_idx   = (const int*)  d_in[3];
  const float* w_down     = (const float*)d_in[4];
  const float* w_up       = (const float*)d_in[5];
  const float* W1         = (const float*)d_in[6];
  const float* b1         = (const float*)d_in[7];
  const float* W2         = (const float*)d_in[8];
  const float* b2         = (const float*)d_in[9];
  float* out = (float*)d_out;

  if (ws_size < WS_NEED) return;

  hipFuncSetAttribute(reinterpret_cast<const void*>(fused_k),
                      hipFuncAttributeMaxDynamicSharedMemorySize, LDSZ);

  unsigned short* img = (unsigned short*)d_ws;
  pack_k<<<(NELEMS + 255) / 256, 256, 0, stream>>>(W1, W2, w_down, w_up, img);
  fused_k<<<NBLK, NTH, LDSZ, stream>>>(x, topk_probs, topk_idx, b1, b2, img, out);
}